// Round 13
// baseline (69.045 us; speedup 1.0000x reference)
//
#include <hip/hip_runtime.h>

// Deimv2LQE: out = scores + MLP(top4-softmax-stats(pred_corners))
// 262144 rows; per row 132 f32 (4 corners x 33 bins).
// R13: intra-wave software pipeline (latency hidden by ILP, not TLP).
//   Block = 128 rows, 4 waves; wave wv owns groups g0=2wv, g1=2wv+1 (16 rows
//   each). Issue g0 loads, g1 loads (18 outstanding) -> write g0 (vmcnt(9),
//   g1 in flight) -> corner g0 (hides g1 latency) -> write g1 -> corner g1.
//   Stats embedded at slice heads [0,336) (lockstep WAR-safe, R12); MLP
//   wave-split by j-slice (s_load weights), 2 rows/lane; partials at even
//   slices [400,528). LDS 67584 B -> 2 blocks/CU (= observed residency all
//   session; bet is per-wave duty, not wave count).

#define THREADS 256
#define BLOCK_ROWS 128

typedef float f32x4 __attribute__((ext_vector_type(4), aligned(16)));

__device__ __forceinline__ void sort4d(float& a, float& b, float& c, float& d) {
    float t;
    t = fmaxf(a, b); b = fminf(a, b); a = t;
    t = fmaxf(c, d); d = fminf(c, d); c = t;
    t = fmaxf(a, c); c = fminf(a, c); a = t;
    t = fmaxf(b, d); d = fminf(b, d); b = t;
    t = fmaxf(b, c); c = fminf(b, c); b = t;
}
__device__ __forceinline__ void ins4(float& a, float& b, float& c, float& d,
                                     float x) {
    float t;
    t = fmaxf(a, x); x = fminf(a, x); a = t;
    t = fmaxf(b, x); x = fminf(b, x); b = t;
    t = fmaxf(c, x); x = fminf(c, x); c = t;
    d = fmaxf(d, x);
}
__device__ __forceinline__ void merge4(float& a0, float& a1, float& a2,
                                       float& a3, float b0, float b1,
                                       float b2, float b3) {
    a0 = fmaxf(a0, b3);
    a1 = fmaxf(a1, b2);
    a2 = fmaxf(a2, b1);
    a3 = fmaxf(a3, b0);
    sort4d(a0, a1, a2, a3);
}

__global__ __launch_bounds__(THREADS, 2)
void lqe_kernel(const float* __restrict__ scores,
                const float* __restrict__ pc,
                const float* __restrict__ w1,
                const float* __restrict__ b1,
                const float* __restrict__ w2,
                const float* __restrict__ b2,
                float* __restrict__ out)
{
    // 8 group-slices of 2112 floats (16 rows x 132). Per slice:
    //   [0,336): stats (16 rows x 21)  -- written after slice x-reads
    //   [400,528) on EVEN slices: MLP partials (128 rows per wave)
    __shared__ float smStage[BLOCK_ROWS * 132];   // 67584 B

    const int t  = threadIdx.x;
    const int wv = t >> 6;
    const int l  = t & 63;
    const long long rowBase = (long long)blockIdx.x * BLOCK_ROWS;

    float sc = 0.f;
    if (t < BLOCK_ROWS) sc = scores[rowBase + t];   // issued first

    const int g0 = 2 * wv, g1 = 2 * wv + 1;

    auto load_g = [&](int g, f32x4 (&r)[8], f32x4& tl) {
        const f32x4* __restrict__ src =
            (const f32x4*)(pc + (rowBase + (long long)g * 16) * 132);
        #pragma unroll
        for (int i = 0; i < 8; ++i) r[i] = src[l + i * 64];
        if (l < 16) tl = src[512 + l];
    };
    auto write_g = [&](int g, const f32x4 (&r)[8], const f32x4& tl) {
        f32x4* dst = (f32x4*)smStage + g * 528;
        #pragma unroll
        for (int i = 0; i < 8; ++i) dst[l + i * 64] = r[i];
        if (l < 16) dst[512 + l] = tl;
    };
    // corner task: lane l -> row (l>>2) of group g, corner (l&3);
    // x at slice+33*l (odd stride, free). Stats to slice head (lockstep-safe).
    auto corner_g = [&](int g) {
        const float* v = smStage + g * 2112 + l * 33;
        float x[33];
        #pragma unroll
        for (int k = 0; k < 33; ++k) x[k] = v[k];

        float a0 = x[0],  a1 = x[1],  a2 = x[2],  a3 = x[3];
        float c0 = x[8],  c1 = x[9],  c2 = x[10], c3 = x[11];
        float d0 = x[16], d1 = x[17], d2 = x[18], d3 = x[19];
        float e0 = x[24], e1 = x[25], e2 = x[26], e3 = x[27];
        sort4d(a0, a1, a2, a3);
        sort4d(c0, c1, c2, c3);
        sort4d(d0, d1, d2, d3);
        sort4d(e0, e1, e2, e3);
        #pragma unroll
        for (int k = 0; k < 4; ++k) {
            ins4(a0, a1, a2, a3, x[4 + k]);
            ins4(c0, c1, c2, c3, x[12 + k]);
            ins4(d0, d1, d2, d3, x[20 + k]);
            ins4(e0, e1, e2, e3, x[28 + k]);
        }
        ins4(e0, e1, e2, e3, x[32]);
        merge4(a0, a1, a2, a3, c0, c1, c2, c3);
        merge4(d0, d1, d2, d3, e0, e1, e2, e3);
        merge4(a0, a1, a2, a3, d0, d1, d2, d3);
        const float t0 = a0, t1 = a1, t2 = a2, t3 = a3;

        float sa = 0.f, sb = 0.f, scc = 0.f, sd = 0.f;
        #pragma unroll
        for (int k = 0; k < 32; k += 4) {
            sa  += __expf(x[k + 0] - t0);
            sb  += __expf(x[k + 1] - t0);
            scc += __expf(x[k + 2] - t0);
            sd  += __expf(x[k + 3] - t0);
        }
        sa += __expf(x[32] - t0);
        const float inv = 1.0f / ((sa + sb) + (scc + sd));
        const float p0 = inv;
        const float p1 = __expf(t1 - t0) * inv;
        const float p2 = __expf(t2 - t0) * inv;
        const float p3 = __expf(t3 - t0) * inv;
        const float pm = 0.25f * (p0 + p1 + p2 + p3);

        float* sd_ = smStage + g * 2112 + (l >> 2) * 21 + (l & 3) * 5;
        sd_[0] = p0; sd_[1] = p1; sd_[2] = p2; sd_[3] = p3; sd_[4] = pm;
    };

    // ---- pipelined stage+corner: g1 latency hidden under corner(g0) ----
    f32x4 ra[8], rb[8], ta, tb;
    load_g(g0, ra, ta);          // 9 loads in flight
    load_g(g1, rb, tb);          // 18 in flight
    write_g(g0, ra, ta);         // waits vmcnt(9): g1 stays in flight
    corner_g(g0);                //   ~800 cyc, hides g1 round-trip
    write_g(g1, rb, tb);         // waits vmcnt(0): already arrived
    corner_g(g1);
    __syncthreads();             // all stats visible

    // ---- MLP: wave wv -> j-slice [16wv,16wv+16), lane=row, 2 rows/lane ----
    {
        const int wvs = __builtin_amdgcn_readfirstlane(wv);
        const float* __restrict__ w1s = w1 + wvs * 16;
        const float* __restrict__ w2s = w2 + wvs * 16;
        const float* __restrict__ b1s = b1 + wvs * 16;

        #pragma unroll
        for (int half = 0; half < 2; ++half) {
            const int r = half * 64 + l;
            float st[20];
            #pragma unroll
            for (int k = 0; k < 20; ++k)
                st[k] = smStage[(r >> 4) * 2112 + (r & 15) * 21 + k];

            float h[16];
            #pragma unroll
            for (int j = 0; j < 16; ++j) h[j] = b1s[j];
            #pragma unroll
            for (int k = 0; k < 20; ++k) {
                #pragma unroll
                for (int j = 0; j < 16; ++j)
                    h[j] = fmaf(st[k], w1s[k * 64 + j], h[j]);
            }
            float acc0 = 0.f, acc1 = 0.f, acc2 = 0.f, acc3 = 0.f;
            #pragma unroll
            for (int j = 0; j < 16; j += 4) {
                acc0 = fmaf(fmaxf(h[j + 0], 0.f), w2s[j + 0], acc0);
                acc1 = fmaf(fmaxf(h[j + 1], 0.f), w2s[j + 1], acc1);
                acc2 = fmaf(fmaxf(h[j + 2], 0.f), w2s[j + 2], acc2);
                acc3 = fmaf(fmaxf(h[j + 3], 0.f), w2s[j + 3], acc3);
            }
            // partial for row r into even slice 2wv at [400,528)
            smStage[wvs * 4224 + 400 + r] = (acc0 + acc1) + (acc2 + acc3);
        }
    }
    __syncthreads();

    // ---- reduce 4 wave-partials, add score, coalesced store ----
    if (t < BLOCK_ROWS) {
        const float r = (smStage[400 + t]        + smStage[4224 + 400 + t]) +
                        (smStage[8448 + 400 + t] + smStage[12672 + 400 + t]);
        out[rowBase + t] = sc + r + b2[0];
    }
}

extern "C" void kernel_launch(void* const* d_in, const int* in_sizes, int n_in,
                              void* d_out, int out_size, void* d_ws, size_t ws_size,
                              hipStream_t stream) {
    const float* scores = (const float*)d_in[0];
    const float* pc     = (const float*)d_in[1];
    const float* w1     = (const float*)d_in[2];
    const float* b1     = (const float*)d_in[3];
    const float* w2     = (const float*)d_in[4];
    const float* b2     = (const float*)d_in[5];
    float* out = (float*)d_out;

    const int rows = out_size;              // 262144
    const int blocks = rows / BLOCK_ROWS;   // 2048
    lqe_kernel<<<blocks, THREADS, 0, stream>>>(scores, pc, w1, b1, w2, b2, out);
}

// Round 14
// 39.681 us; speedup vs baseline: 1.7400x; 1.7400x over previous
//
#include <hip/hip_runtime.h>

// Deimv2LQE: out = scores + MLP(top4-softmax-stats(pred_corners))
// 262144 rows; per row 132 f32 (4 corners x 33 bins).
// R14: LDS-DMA double-buffered 2-tile blocks (memory/compute overlap).
//   2048 blocks x 2 tiles x 64 rows. Tile1's global_load_lds DMA (9 instr,
//   no VGPR round-trip) issued BEFORE tile0's compute and pinned with
//   sched_barrier(0); mid-iteration barriers are lgkmcnt-only so the DMA
//   stays in flight; the inter-tile __syncthreads is the single drain point.
//   Stats/partials embedded in the live tile's buffer (R12): LDS = 2x33792.
//   Compute bodies = R9 (ILP top-4, 4-acc exp, wave-split s_load MLP).

#define THREADS 256

typedef float f32x4 __attribute__((ext_vector_type(4), aligned(16)));

#define BAR_LGKM() asm volatile("s_waitcnt lgkmcnt(0)\n\ts_barrier" ::: "memory")

__device__ __forceinline__ void sort4d(float& a, float& b, float& c, float& d) {
    float t;
    t = fmaxf(a, b); b = fminf(a, b); a = t;
    t = fmaxf(c, d); d = fminf(c, d); c = t;
    t = fmaxf(a, c); c = fminf(a, c); a = t;
    t = fmaxf(b, d); d = fminf(b, d); b = t;
    t = fmaxf(b, c); c = fminf(b, c); b = t;
}
__device__ __forceinline__ void ins4(float& a, float& b, float& c, float& d,
                                     float x) {
    float t;
    t = fmaxf(a, x); x = fminf(a, x); a = t;
    t = fmaxf(b, x); x = fminf(b, x); b = t;
    t = fmaxf(c, x); x = fminf(c, x); c = t;
    d = fmaxf(d, x);
}
__device__ __forceinline__ void merge4(float& a0, float& a1, float& a2,
                                       float& a3, float b0, float b1,
                                       float b2, float b3) {
    a0 = fmaxf(a0, b3);
    a1 = fmaxf(a1, b2);
    a2 = fmaxf(a2, b1);
    a3 = fmaxf(a3, b0);
    sort4d(a0, a1, a2, a3);
}

// DMA one 64-row tile (2112 f4) into buf. LDS dest: wave-uniform base +
// lane*16 (m104 constraint); global src per-lane, fully coalesced.
__device__ __forceinline__ void stage_dma(const float* __restrict__ gsrc,
                                          float (&buf)[8448], int t) {
    const int wvbase = t & 192;   // wv*64
    #pragma unroll
    for (int i = 0; i < 8; ++i)
        __builtin_amdgcn_global_load_lds(
            (const __attribute__((address_space(1))) void*)(gsrc + (size_t)(i * 256 + t) * 4),
            (__attribute__((address_space(3))) void*)(&buf[(i * 256 + wvbase) * 4]),
            16, 0, 0);
    if (t < 64)
        __builtin_amdgcn_global_load_lds(
            (const __attribute__((address_space(1))) void*)(gsrc + (size_t)(2048 + t) * 4),
            (__attribute__((address_space(3))) void*)(&buf[2048 * 4]),
            16, 0, 0);
}

// corner task t: row t>>2, corner t&3 -> x at buf+33t (odd stride, free).
// stats into OWN wave's slice head [wv*2112, +336): all x-reads precede
// stat-writes in program order, lanes lockstep -> WAR-safe in-wave.
__device__ __forceinline__ void corner_tile(float (&buf)[8448], int t) {
    const float* v = &buf[t * 33];
    float x[33];
    #pragma unroll
    for (int k = 0; k < 33; ++k) x[k] = v[k];

    float a0 = x[0],  a1 = x[1],  a2 = x[2],  a3 = x[3];
    float c0 = x[8],  c1 = x[9],  c2 = x[10], c3 = x[11];
    float d0 = x[16], d1 = x[17], d2 = x[18], d3 = x[19];
    float e0 = x[24], e1 = x[25], e2 = x[26], e3 = x[27];
    sort4d(a0, a1, a2, a3);
    sort4d(c0, c1, c2, c3);
    sort4d(d0, d1, d2, d3);
    sort4d(e0, e1, e2, e3);
    #pragma unroll
    for (int k = 0; k < 4; ++k) {
        ins4(a0, a1, a2, a3, x[4 + k]);
        ins4(c0, c1, c2, c3, x[12 + k]);
        ins4(d0, d1, d2, d3, x[20 + k]);
        ins4(e0, e1, e2, e3, x[28 + k]);
    }
    ins4(e0, e1, e2, e3, x[32]);
    merge4(a0, a1, a2, a3, c0, c1, c2, c3);
    merge4(d0, d1, d2, d3, e0, e1, e2, e3);
    merge4(a0, a1, a2, a3, d0, d1, d2, d3);
    const float t0 = a0, t1 = a1, t2 = a2, t3 = a3;

    float sa = 0.f, sb = 0.f, scc = 0.f, sd = 0.f;
    #pragma unroll
    for (int k = 0; k < 32; k += 4) {
        sa  += __expf(x[k + 0] - t0);
        sb  += __expf(x[k + 1] - t0);
        scc += __expf(x[k + 2] - t0);
        sd  += __expf(x[k + 3] - t0);
    }
    sa += __expf(x[32] - t0);
    const float inv = 1.0f / ((sa + sb) + (scc + sd));
    const float p0 = inv;
    const float p1 = __expf(t1 - t0) * inv;
    const float p2 = __expf(t2 - t0) * inv;
    const float p3 = __expf(t3 - t0) * inv;
    const float pm = 0.25f * (p0 + p1 + p2 + p3);

    float* sd_ = &buf[(t & 192) * 33 + ((t >> 2) & 15) * 21 + (t & 3) * 5];
    sd_[0] = p0; sd_[1] = p1; sd_[2] = p2; sd_[3] = p3; sd_[4] = pm;
}

// MLP: wave wv -> hidden slice [16wv,16wv+16), lane = row; partial into
// own slice at [400,464) (disjoint from stats [0,336) -> race-free).
__device__ __forceinline__ void mlp_tile(float (&buf)[8448], int t,
                                         const float* __restrict__ w1,
                                         const float* __restrict__ b1,
                                         const float* __restrict__ w2) {
    const int l = t & 63;
    const int wvs = __builtin_amdgcn_readfirstlane(t >> 6);
    const float* __restrict__ w1s = w1 + wvs * 16;
    const float* __restrict__ w2s = w2 + wvs * 16;
    const float* __restrict__ b1s = b1 + wvs * 16;

    float st[20];
    #pragma unroll
    for (int k = 0; k < 20; ++k)
        st[k] = buf[(l >> 4) * 2112 + (l & 15) * 21 + k];

    float h[16];
    #pragma unroll
    for (int j = 0; j < 16; ++j) h[j] = b1s[j];
    #pragma unroll
    for (int k = 0; k < 20; ++k) {
        #pragma unroll
        for (int j = 0; j < 16; ++j)
            h[j] = fmaf(st[k], w1s[k * 64 + j], h[j]);
    }
    float acc0 = 0.f, acc1 = 0.f, acc2 = 0.f, acc3 = 0.f;
    #pragma unroll
    for (int j = 0; j < 16; j += 4) {
        acc0 = fmaf(fmaxf(h[j + 0], 0.f), w2s[j + 0], acc0);
        acc1 = fmaf(fmaxf(h[j + 1], 0.f), w2s[j + 1], acc1);
        acc2 = fmaf(fmaxf(h[j + 2], 0.f), w2s[j + 2], acc2);
        acc3 = fmaf(fmaxf(h[j + 3], 0.f), w2s[j + 3], acc3);
    }
    buf[wvs * 2112 + 400 + l] = (acc0 + acc1) + (acc2 + acc3);
}

__device__ __forceinline__ float reduce4(float (&buf)[8448], int t) {
    return (buf[400 + t] + buf[2512 + t]) + (buf[4624 + t] + buf[6736 + t]);
}

__global__ __launch_bounds__(THREADS, 2)
void lqe_kernel(const float* __restrict__ scores,
                const float* __restrict__ pc,
                const float* __restrict__ w1,
                const float* __restrict__ b1,
                const float* __restrict__ w2,
                const float* __restrict__ b2,
                float* __restrict__ out)
{
    __shared__ float smA[8448];   // 33792 B  (tile data + stats + partials)
    __shared__ float smB[8448];   // 33792 B

    const int t = threadIdx.x;
    const long long blockRow0 = (long long)blockIdx.x * 128;
    const float b2v = b2[0];

    // score loads issued first (deep in queue, drained by first barrier)
    float sc0 = 0.f, sc1 = 0.f;
    if (t < 64) {
        sc0 = scores[blockRow0 + t];
        sc1 = scores[blockRow0 + 64 + t];
    }

    // prologue: DMA tile0
    stage_dma(pc + blockRow0 * 132, smA, t);
    __syncthreads();                          // drains own DMA, all waves

    // ---- tile 0 on smA; tile 1 DMA in flight underneath ----
    stage_dma(pc + (blockRow0 + 64) * 132, smB, t);
    __builtin_amdgcn_sched_barrier(0);        // pin DMA issue before compute
    corner_tile(smA, t);
    BAR_LGKM();                               // stats visible; DMA in flight
    mlp_tile(smA, t, w1, b1, w2);
    BAR_LGKM();
    if (t < 64) out[blockRow0 + t] = sc0 + reduce4(smA, t) + b2v;
    __syncthreads();                          // drains DMA(tile1) + store

    // ---- tile 1 on smB ----
    corner_tile(smB, t);
    BAR_LGKM();
    mlp_tile(smB, t, w1, b1, w2);
    BAR_LGKM();
    if (t < 64) out[blockRow0 + 64 + t] = sc1 + reduce4(smB, t) + b2v;
}

extern "C" void kernel_launch(void* const* d_in, const int* in_sizes, int n_in,
                              void* d_out, int out_size, void* d_ws, size_t ws_size,
                              hipStream_t stream) {
    const float* scores = (const float*)d_in[0];
    const float* pc     = (const float*)d_in[1];
    const float* w1     = (const float*)d_in[2];
    const float* b1     = (const float*)d_in[3];
    const float* w2     = (const float*)d_in[4];
    const float* b2     = (const float*)d_in[5];
    float* out = (float*)d_out;

    const int rows = out_size;          // 262144
    const int blocks = rows / 128;      // 2048
    lqe_kernel<<<blocks, THREADS, 0, stream>>>(scores, pc, w1, b1, w2, b2, out);
}